// Round 13
// baseline (1656.251 us; speedup 1.0000x reference)
//
#include <hip/hip_runtime.h>

#define D 128
#define NEIGH 16
#define SINKI 20
#define TINYF 1e-30f

typedef __attribute__((ext_vector_type(8))) _Float16 f16x8;
typedef __attribute__((ext_vector_type(4))) float f32x4;
typedef __attribute__((ext_vector_type(2))) unsigned int u32x2;

// DPP rotate within 16-lane row: ror by N lanes; chain of 4 = broadcast row sum.
template <int N>
__device__ __forceinline__ float rorf(float v) {
  int r = __builtin_amdgcn_update_dpp(0, __builtin_bit_cast(int, v),
                                      0x120 + N, 0xf, 0xf, true);
  return __builtin_bit_cast(float, r);
}

// f16 row k (256B), byte-swizzle ^((k&15)<<4); read 16B e-slice (ks,g)
__device__ __forceinline__ f16x8 ldfrag(const _Float16* U, int k, int ks, int g) {
  return *(const f16x8*)((const char*)U + k * 256 + (((ks << 6) + (g << 4)) ^ ((k & 15) << 4)));
}

// write f16 U[k][d0..d0+3], d0 = 16rt+4g, same swizzle; RTE casts
__device__ __forceinline__ void stquad(_Float16* U, int k, int rt, int g,
                                       float x, float y, float z, float w) {
  union { _Float16 h[4]; u32x2 u; } P;
  P.h[0] = (_Float16)x; P.h[1] = (_Float16)y;
  P.h[2] = (_Float16)z; P.h[3] = (_Float16)w;
  *(u32x2*)((char*)U + k * 256 + (((rt << 5) + (g << 3)) ^ ((k & 15) << 4))) = P.u;
}

// f32 self-buffer [16 rows][128 d] (512B rows): byte offset with bank swizzle
// (row stride 512B == 0 mod 32 banks -> XOR row bits into the 16B-slot bits)
__device__ __forceinline__ int selfoff(int j, int rowbyte) {
  return j * 512 + (rowbyte ^ (((j & 3) << 4) | ((j >> 2) << 6)));
}

// block = 512 thr = 8 slots (1 wave each). A block processes 16 nodes (8 pairs)
// per batch. Slot s owns the 2 neighbor tiles of nodes nA=16b+2s, nB=nA+1.
// The 16 self-distributions form ONE shared 16-column tile, split by d-slice:
// slot w computes rt=w of it (4 MFMA vs 32) -> self work amortized 8x.
// LDS: KB 32K + KA 32K + Us 64K + UselfU 4K + UselfV 4K + MuSelf 8K + SelfKv 8K = 152KB.
__global__ __launch_bounds__(512, 1)
void wgcn_hop(const float* __restrict__ Xin,
              const float* __restrict__ Cmat,
              const int* __restrict__ neigh,
              float* __restrict__ Xout,
              int n_batches) {
  __shared__ _Float16 KB[16384];   // MM1 A-frags: Khat[e=32ks+8g+s][d=16rt+c]
  __shared__ _Float16 KA[16384];   // MM2 A-frags: Khat[d=16rt+c][e=32ks+8g+s]
  __shared__ _Float16 Us8[8][4096];// per-slot u/v, rows 0..15 = A-neigh, 16..31 = B-neigh
  __shared__ _Float16 UselfU[2048];// shared self rows (u), [16][128] f16 swizzled
  __shared__ _Float16 UselfV[2048];// shared self rows (v)
  __shared__ float    MuSelf[2048];// normalized self mu, f32 swizzled
  __shared__ float    SelfKv[2048];// Kv_self staging, f32 swizzled

  const int tid = threadIdx.x;

  for (int idx = tid; idx < 16384; idx += 512) {
    const int sI = idx & 7, cI = (idx >> 3) & 15, gI = (idx >> 7) & 3;
    const int rtI = (idx >> 9) & 7, ksI = idx >> 12;
    const int e = (ksI << 5) + (gI << 3) + sI;
    const int d = (rtI << 4) + cI;
    KB[idx] = (_Float16)(16.0f * expf(-10.0f * Cmat[e * 128 + d]));
    KA[idx] = (_Float16)(16.0f * expf(-10.0f * Cmat[d * 128 + e]));
  }
  // first __syncthreads below (end of gather) orders K staging vs all MFMA use

  const int slot = tid >> 6;
  const int lane = tid & 63;
  const int g = lane >> 4;
  const int c = lane & 15;
  _Float16* Us = Us8[slot];

  for (int b = blockIdx.x; b < n_batches; b += gridDim.x) {
    const int nA = b * 16 + 2 * slot, nB = nA + 1;

    // ---- gather: neighbor mu kept in registers; self mu staged to LDS ----
    f32x4 mu0[8], mu1[8];
    {
      f32x4 muS[8];
      const int srcA = neigh[nA * NEIGH + c];
      const int srcB = neigh[nB * NEIGH + c];
      const int srcS = (c == 1) ? nB : nA;
      float s0 = 0.f, s1 = 0.f, sS = 0.f;
#pragma unroll
      for (int rt = 0; rt < 8; ++rt) {
        mu0[rt] = *(const f32x4*)&Xin[(long)srcA * D + rt * 16 + g * 4];
        mu1[rt] = *(const f32x4*)&Xin[(long)srcB * D + rt * 16 + g * 4];
        muS[rt] = *(const f32x4*)&Xin[(long)srcS * D + rt * 16 + g * 4];
        s0 += mu0[rt].x + mu0[rt].y + mu0[rt].z + mu0[rt].w;
        s1 += mu1[rt].x + mu1[rt].y + mu1[rt].z + mu1[rt].w;
        sS += muS[rt].x + muS[rt].y + muS[rt].z + muS[rt].w;
      }
      s0 += __shfl_xor(s0, 16, 64); s0 += __shfl_xor(s0, 32, 64);
      s1 += __shfl_xor(s1, 16, 64); s1 += __shfl_xor(s1, 32, 64);
      sS += __shfl_xor(sS, 16, 64); sS += __shfl_xor(sS, 32, 64);
      const float i0 = 1024.0f * __builtin_amdgcn_rcpf(s0 + TINYF);
      const float i1 = 1024.0f * __builtin_amdgcn_rcpf(s1 + TINYF);
      const float iS = 1024.0f * __builtin_amdgcn_rcpf(sS + TINYF);
#pragma unroll
      for (int rt = 0; rt < 8; ++rt) {
        mu0[rt].x *= i0; mu0[rt].y *= i0; mu0[rt].z *= i0; mu0[rt].w *= i0;
        mu1[rt].x *= i1; mu1[rt].y *= i1; mu1[rt].z *= i1; mu1[rt].w *= i1;
      }
      if (c < 2) {
        const int jme = 2 * slot + c;
#pragma unroll
        for (int rt = 0; rt < 8; ++rt) {
          f32x4 m = muS[rt];
          m.x *= iS; m.y *= iS; m.z *= iS; m.w *= iS;
          *(f32x4*)((char*)MuSelf + selfoff(jme, (rt << 6) | (g << 4))) = m;
        }
      }
    }

    // ---- u0 = 1: own 32 neighbor rows; self rows 2s,2s+1 ----
#pragma unroll
    for (int j = 0; j < 32; ++j)
      ((unsigned int*)Us)[(j << 6) | lane] = 0x3C003C00u;
    ((unsigned int*)UselfU)[((2 * slot) << 6) | lane] = 0x3C003C00u;
    ((unsigned int*)UselfU)[((2 * slot + 1) << 6) | lane] = 0x3C003C00u;
    __syncthreads();

#pragma unroll 1
    for (int it = 0; it < SINKI; ++it) {
      // ======== MM1: KTu'[d][k] = sum_e Khat[e][d] * u[k][e] ========
      f16x8 b0[4], b1[4], b2[4];
#pragma unroll
      for (int ks = 0; ks < 4; ++ks) {
        b0[ks] = ldfrag(Us, c, ks, g);
        b1[ks] = ldfrag(Us, 16 + c, ks, g);
        b2[ks] = ldfrag(UselfU, c, ks, g);
      }
      { // shared self tile, own d-slice rt = slot
        f32x4 a2 = {0.f, 0.f, 0.f, 0.f};
#pragma unroll
        for (int ks = 0; ks < 4; ++ks) {
          const f16x8 af = *(const f16x8*)&KB[((((ks << 3) + slot) << 6) + lane) << 3];
          a2 = __builtin_amdgcn_mfma_f32_16x16x32_f16(af, b2[ks], a2, 0, 0, 0);
        }
        const f32x4 ms = *(const f32x4*)((const char*)MuSelf + selfoff(c, (slot << 6) | (g << 4)));
        stquad(UselfV, c, slot, g,
               ms.x * __builtin_amdgcn_rcpf(a2.x),
               ms.y * __builtin_amdgcn_rcpf(a2.y),
               ms.z * __builtin_amdgcn_rcpf(a2.z),
               ms.w * __builtin_amdgcn_rcpf(a2.w));
      }
#pragma unroll
      for (int rt = 0; rt < 8; ++rt) {
        f32x4 a0 = {0.f, 0.f, 0.f, 0.f}, a1 = a0;
#pragma unroll
        for (int ks = 0; ks < 4; ++ks) {
          const f16x8 af = *(const f16x8*)&KB[((((ks << 3) + rt) << 6) + lane) << 3];
          a0 = __builtin_amdgcn_mfma_f32_16x16x32_f16(af, b0[ks], a0, 0, 0, 0);
          a1 = __builtin_amdgcn_mfma_f32_16x16x32_f16(af, b1[ks], a1, 0, 0, 0);
        }
        stquad(Us, c, rt, g,
               mu0[rt].x * __builtin_amdgcn_rcpf(a0.x),
               mu0[rt].y * __builtin_amdgcn_rcpf(a0.y),
               mu0[rt].z * __builtin_amdgcn_rcpf(a0.z),
               mu0[rt].w * __builtin_amdgcn_rcpf(a0.w));
        stquad(Us, 16 + c, rt, g,
               mu1[rt].x * __builtin_amdgcn_rcpf(a1.x),
               mu1[rt].y * __builtin_amdgcn_rcpf(a1.y),
               mu1[rt].z * __builtin_amdgcn_rcpf(a1.z),
               mu1[rt].w * __builtin_amdgcn_rcpf(a1.w));
      }
      __syncthreads();   // (1) all v rows (incl. v_self slices) complete

      // ======== MM2: Kv'[d][k] = sum_e Khat[d][e] * v[k][e] ========
#pragma unroll
      for (int ks = 0; ks < 4; ++ks) {
        b0[ks] = ldfrag(Us, c, ks, g);
        b1[ks] = ldfrag(Us, 16 + c, ks, g);
        b2[ks] = ldfrag(UselfV, c, ks, g);
      }
      { // shared self tile slice -> stage Kv_self to LDS (f32)
        f32x4 a2 = {0.f, 0.f, 0.f, 0.f};
#pragma unroll
        for (int ks = 0; ks < 4; ++ks) {
          const f16x8 af = *(const f16x8*)&KA[((((ks << 3) + slot) << 6) + lane) << 3];
          a2 = __builtin_amdgcn_mfma_f32_16x16x32_f16(af, b2[ks], a2, 0, 0, 0);
        }
        *(f32x4*)((char*)SelfKv + selfoff(c, (slot << 6) | (g << 4))) = a2;
      }
      f32x4 h0[8], h1[8];
#pragma unroll
      for (int rt = 0; rt < 8; ++rt) {
        f32x4 a0 = {0.f, 0.f, 0.f, 0.f}, a1 = a0;
#pragma unroll
        for (int ks = 0; ks < 4; ++ks) {
          const f16x8 af = *(const f16x8*)&KA[((((ks << 3) + rt) << 6) + lane) << 3];
          a0 = __builtin_amdgcn_mfma_f32_16x16x32_f16(af, b0[ks], a0, 0, 0, 0);
          a1 = __builtin_amdgcn_mfma_f32_16x16x32_f16(af, b1[ks], a1, 0, 0, 0);
        }
        h0[rt] = a0; h1[rt] = a1;
      }
      __syncthreads();   // (2) SelfKv complete

      // ======== epilogue: b = geomean over 17, u = b/Kv ========
      const int jme = 2 * slot + c;   // valid for c < 2
#pragma unroll
      for (int rt = 0; rt < 8; ++rt) {
        f32x4 sv = {1.f, 1.f, 1.f, 1.f};
        if (c < 2)
          sv = *(const f32x4*)((const char*)SelfKv + selfoff(jme, (rt << 6) | (g << 4)));
        float bA[4], bB[4];
#pragma unroll
        for (int r = 0; r < 4; ++r) {
          const float tA = ((const float*)&h0[rt])[r];
          const float tB = ((const float*)&h1[rt])[r];
          const float svr = ((const float*)&sv)[r];
          float fA = (c == 0) ? tA * svr : tA;   // fold self-A at lane c==0
          float fB = (c == 1) ? tB * svr : tB;   // fold self-B at lane c==1
          float pA = __builtin_amdgcn_logf(fA);
          float pB = __builtin_amdgcn_logf(fB);
          pA += rorf<1>(pA); pA += rorf<2>(pA); pA += rorf<4>(pA); pA += rorf<8>(pA);
          pB += rorf<1>(pB); pB += rorf<2>(pB); pB += rorf<4>(pB); pB += rorf<8>(pB);
          bA[r] = __builtin_amdgcn_exp2f(pA * (1.0f / 17.0f));
          bB[r] = __builtin_amdgcn_exp2f(pB * (1.0f / 17.0f));
        }
        if (it < SINKI - 1) {
          stquad(Us, c, rt, g,
                 bA[0] * __builtin_amdgcn_rcpf(((const float*)&h0[rt])[0]),
                 bA[1] * __builtin_amdgcn_rcpf(((const float*)&h0[rt])[1]),
                 bA[2] * __builtin_amdgcn_rcpf(((const float*)&h0[rt])[2]),
                 bA[3] * __builtin_amdgcn_rcpf(((const float*)&h0[rt])[3]));
          stquad(Us, 16 + c, rt, g,
                 bB[0] * __builtin_amdgcn_rcpf(((const float*)&h1[rt])[0]),
                 bB[1] * __builtin_amdgcn_rcpf(((const float*)&h1[rt])[1]),
                 bB[2] * __builtin_amdgcn_rcpf(((const float*)&h1[rt])[2]),
                 bB[3] * __builtin_amdgcn_rcpf(((const float*)&h1[rt])[3]));
          if (c < 2) {
            const float q0 = ((c == 0) ? bA[0] : bB[0]) * __builtin_amdgcn_rcpf(((const float*)&sv)[0]);
            const float q1 = ((c == 0) ? bA[1] : bB[1]) * __builtin_amdgcn_rcpf(((const float*)&sv)[1]);
            const float q2 = ((c == 0) ? bA[2] : bB[2]) * __builtin_amdgcn_rcpf(((const float*)&sv)[2]);
            const float q3 = ((c == 0) ? bA[3] : bB[3]) * __builtin_amdgcn_rcpf(((const float*)&sv)[3]);
            stquad(UselfU, jme, rt, g, q0, q1, q2, q3);
          }
        } else if (c < 2) {
          float* dst = &Xout[(long)((c == 0) ? nA : nB) * D + rt * 16 + g * 4];
          f32x4 o;
          o.x = ((c == 0) ? bA[0] : bB[0]) * (1.0f / 1024.0f);
          o.y = ((c == 0) ? bA[1] : bB[1]) * (1.0f / 1024.0f);
          o.z = ((c == 0) ? bA[2] : bB[2]) * (1.0f / 1024.0f);
          o.w = ((c == 0) ? bA[3] : bB[3]) * (1.0f / 1024.0f);
          *(f32x4*)dst = o;
        }
      }
      __syncthreads();   // (3) u rows (incl. u_self) complete
    }
  }
}

extern "C" void kernel_launch(void* const* d_in, const int* in_sizes, int n_in,
                              void* d_out, int out_size, void* d_ws, size_t ws_size,
                              hipStream_t stream) {
  const float* trans_X = (const float*)d_in[0];
  const float* cost = (const float*)d_in[1];
  const int* neigh = (const int*)d_in[2];
  float* out = (float*)d_out;
  float* X1 = (float*)d_ws;   // intermediate hop output, 20000*128 f32
  const int n = in_sizes[0] / D;
  const int n_batches = n / 16;   // N = 20000 -> 1250 batches of 16 nodes

  dim3 grid(250), block(512);    // 5 batches per block
  hipLaunchKernelGGL(wgcn_hop, grid, block, 0, stream, trans_X, cost, neigh, X1, n_batches);
  hipLaunchKernelGGL(wgcn_hop, grid, block, 0, stream, X1, cost, neigh, out, n_batches);
}